// Round 1
// baseline (137.584 us; speedup 1.0000x reference)
//
#include <hip/hip_runtime.h>
#include <math.h>

#define BB 2
#define NAT 2048
#define NTOK 256

struct WS {
  // 73 doubles of scalar state (zeroed each launch)
  double red[BB][17];   // n, swm, Swm_x[3], Swm_xgt[3], M[9]=Swm*x_i*xgt_j
  double Rm[BB][9];     // rotation
  double mu[BB][3];     // mean of x_gt
  double mug[BB][3];    // mean of x
  double mse_num;       // global numerator (sums over batch too, per reference)
  double bond_num[BB];
  double bond_den[BB];
  double cem[BB];
  double cm[BB];
  // per-atom derived arrays
  float w[BB*NAT];
  float nuc[BB*NAT];
  float lig[BB*NAT];
  float pol[BB*NAT];
  int   tok[BB*NAT];
};

__global__ void k_init(WS* ws) {
  double* p = (double*)ws;
  const int nd = 73;  // all doubles above the float arrays
  for (int k = threadIdx.x; k < nd; k += blockDim.x) p[k] = 0.0;
}

// one thread per atom: extract token id from one-hot row, gather token tables
__global__ void k_atom(const float* __restrict__ A, const float* __restrict__ poly,
                       const float* __restrict__ lig, const float* __restrict__ dna,
                       const float* __restrict__ rna, WS* __restrict__ ws) {
  int idx = blockIdx.x * blockDim.x + threadIdx.x;
  if (idx >= BB * NAT) return;
  int b = idx / NAT;
  const float4* row = (const float4*)(A + (size_t)idx * NTOK);
  int t = 0;
  for (int i = 0; i < NTOK / 4; i++) {
    float4 v = row[i];
    if (v.x > 0.5f) t = 4 * i;
    else if (v.y > 0.5f) t = 4 * i + 1;
    else if (v.z > 0.5f) t = 4 * i + 2;
    else if (v.w > 0.5f) t = 4 * i + 3;
  }
  float d = dna[b * NTOK + t], r = rna[b * NTOK + t];
  float li = lig[b * NTOK + t], po = poly[b * NTOK + t];
  ws->w[idx]   = 1.0f + 5.0f * d + 5.0f * r + 10.0f * li;
  ws->nuc[idx] = d + r;
  ws->lig[idx] = li;
  ws->pol[idx] = po;
  ws->tok[idx] = t;
}

// one block per batch: 17 weighted moments for the rigid alignment
__global__ void k_red(const float* __restrict__ x, const float* __restrict__ xgt,
                      const float* __restrict__ mask, WS* __restrict__ ws) {
  int b = blockIdx.x;
  int tid = threadIdx.x;
  double acc[17];
  for (int k = 0; k < 17; k++) acc[k] = 0.0;
  for (int a = tid; a < NAT; a += blockDim.x) {
    float m = mask[b * NAT + a];
    if (m == 0.0f) continue;
    float wv = ws->w[b * NAT + a];
    float wm = wv * m;
    const float* xp = x + ((size_t)b * NAT + a) * 3;
    const float* gp = xgt + ((size_t)b * NAT + a) * 3;
    double x0 = xp[0], x1 = xp[1], x2 = xp[2];
    double g0 = gp[0], g1 = gp[1], g2 = gp[2];
    acc[0] += m;
    acc[1] += wm;
    acc[2] += wm * x0; acc[3] += wm * x1; acc[4] += wm * x2;
    acc[5] += wm * g0; acc[6] += wm * g1; acc[7] += wm * g2;
    acc[8]  += wm * x0 * g0; acc[9]  += wm * x0 * g1; acc[10] += wm * x0 * g2;
    acc[11] += wm * x1 * g0; acc[12] += wm * x1 * g1; acc[13] += wm * x1 * g2;
    acc[14] += wm * x2 * g0; acc[15] += wm * x2 * g1; acc[16] += wm * x2 * g2;
  }
  __shared__ double sd[256];
  for (int k = 0; k < 17; k++) {
    sd[tid] = acc[k];
    __syncthreads();
    for (int s = 128; s > 0; s >>= 1) {
      if (tid < s) sd[tid] += sd[tid + s];
      __syncthreads();
    }
    if (tid == 0) ws->red[b][k] = sd[0];
    __syncthreads();
  }
}

// tiny: 3x3 SVD (Jacobi on H^T H, f64) -> R, means.  One thread per batch.
__global__ void k_svd(WS* ws) {
  int b = threadIdx.x;
  if (b >= BB) return;
  const double* red = ws->red[b];
  double swm = red[1];
  double mug[3] = { red[2] / swm, red[3] / swm, red[4] / swm };  // mean of x
  double mu[3]  = { red[5] / swm, red[6] / swm, red[7] / swm };  // mean of x_gt
  double H[3][3];
  for (int i = 0; i < 3; i++)
    for (int j = 0; j < 3; j++)
      H[i][j] = red[8 + 3 * i + j] - swm * mug[i] * mu[j];
  // K = H^T H
  double Km[3][3];
  for (int i = 0; i < 3; i++)
    for (int j = 0; j < 3; j++)
      Km[i][j] = H[0][i] * H[0][j] + H[1][i] * H[1][j] + H[2][i] * H[2][j];
  double V[3][3] = {{1,0,0},{0,1,0},{0,0,1}};
  for (int sweep = 0; sweep < 30; sweep++) {
    for (int p = 0; p < 2; p++) {
      for (int q = p + 1; q < 3; q++) {
        double apq = Km[p][q];
        if (fabs(apq) < 1e-300) continue;
        double theta = (Km[q][q] - Km[p][p]) / (2.0 * apq);
        double t = 1.0 / (fabs(theta) + sqrt(theta * theta + 1.0));
        if (theta < 0) t = -t;
        double c = 1.0 / sqrt(t * t + 1.0), s = t * c;
        for (int k = 0; k < 3; k++) {  // right-mult by J (columns p,q)
          double akp = Km[k][p], akq = Km[k][q];
          Km[k][p] = c * akp - s * akq;
          Km[k][q] = s * akp + c * akq;
        }
        for (int k = 0; k < 3; k++) {  // left-mult by J^T (rows p,q)
          double apk = Km[p][k], aqk = Km[q][k];
          Km[p][k] = c * apk - s * aqk;
          Km[q][k] = s * apk + c * aqk;
        }
        for (int k = 0; k < 3; k++) {
          double vkp = V[k][p], vkq = V[k][q];
          V[k][p] = c * vkp - s * vkq;
          V[k][q] = s * vkp + c * vkq;
        }
      }
    }
  }
  double ev[3] = { Km[0][0], Km[1][1], Km[2][2] };
  int id[3] = {0, 1, 2};
  for (int i = 0; i < 2; i++)
    for (int j = i + 1; j < 3; j++)
      if (ev[id[j]] > ev[id[i]]) { int tmp = id[i]; id[i] = id[j]; id[j] = tmp; }
  double Uc[3][3], Vc[3][3], S[3];
  for (int k = 0; k < 3; k++) {
    int e = id[k];
    double v0 = V[0][e], v1 = V[1][e], v2 = V[2][e];
    Vc[k][0] = v0; Vc[k][1] = v1; Vc[k][2] = v2;
    double u0 = H[0][0]*v0 + H[0][1]*v1 + H[0][2]*v2;
    double u1 = H[1][0]*v0 + H[1][1]*v1 + H[1][2]*v2;
    double u2 = H[2][0]*v0 + H[2][1]*v1 + H[2][2]*v2;
    double nrm = sqrt(u0*u0 + u1*u1 + u2*u2);
    S[k] = nrm;
    if (nrm > 1e-12) { u0 /= nrm; u1 /= nrm; u2 /= nrm; }
    Uc[k][0] = u0; Uc[k][1] = u1; Uc[k][2] = u2;
  }
  if (S[2] <= 1e-12 * (S[0] > 0 ? S[0] : 1.0)) {  // degenerate fallback
    Uc[2][0] = Uc[0][1]*Uc[1][2] - Uc[0][2]*Uc[1][1];
    Uc[2][1] = Uc[0][2]*Uc[1][0] - Uc[0][0]*Uc[1][2];
    Uc[2][2] = Uc[0][0]*Uc[1][1] - Uc[0][1]*Uc[1][0];
  }
  double detU = Uc[0][0]*(Uc[1][1]*Uc[2][2]-Uc[1][2]*Uc[2][1])
              - Uc[1][0]*(Uc[0][1]*Uc[2][2]-Uc[0][2]*Uc[2][1])
              + Uc[2][0]*(Uc[0][1]*Uc[1][2]-Uc[0][2]*Uc[1][1]);
  double detV = Vc[0][0]*(Vc[1][1]*Vc[2][2]-Vc[1][2]*Vc[2][1])
              - Vc[1][0]*(Vc[0][1]*Vc[2][2]-Vc[0][2]*Vc[2][1])
              + Vc[2][0]*(Vc[0][1]*Vc[1][2]-Vc[0][2]*Vc[1][1]);
  double dsign = (detU * detV < 0.0) ? -1.0 : 1.0;
  for (int i = 0; i < 3; i++)
    for (int j = 0; j < 3; j++)
      ws->Rm[b][3*i+j] = Uc[0][i]*Vc[0][j] + Uc[1][i]*Vc[1][j] + dsign*Uc[2][i]*Vc[2][j];
  for (int i = 0; i < 3; i++) { ws->mu[b][i] = mu[i]; ws->mug[b][i] = mug[i]; }
}

// weighted MSE numerator (global sum, per reference semantics)
__global__ void k_mse(const float* __restrict__ x, const float* __restrict__ xgt,
                      const float* __restrict__ mask, WS* __restrict__ ws) {
  int idx = blockIdx.x * blockDim.x + threadIdx.x;
  double v = 0.0;
  if (idx < BB * NAT) {
    int b = idx / NAT;
    float m = mask[idx];
    if (m != 0.0f) {
      const double* R = ws->Rm[b];
      const double* mu = ws->mu[b];
      const double* mug = ws->mug[b];
      const float* gp = xgt + (size_t)idx * 3;
      const float* xp = x + (size_t)idx * 3;
      double c0 = (double)gp[0] - mu[0];
      double c1 = (double)gp[1] - mu[1];
      double c2 = (double)gp[2] - mu[2];
      double a0 = R[0]*c0 + R[1]*c1 + R[2]*c2 + mug[0];
      double a1 = R[3]*c0 + R[4]*c1 + R[5]*c2 + mug[1];
      double a2 = R[6]*c0 + R[7]*c1 + R[8]*c2 + mug[2];
      double d0 = (double)xp[0] - a0, d1 = (double)xp[1] - a1, d2 = (double)xp[2] - a2;
      v = (double)ws->w[idx] * (double)m * (d0*d0 + d1*d1 + d2*d2);
    }
  }
  __shared__ double sd[256];
  sd[threadIdx.x] = v;
  __syncthreads();
  for (int s = 128; s > 0; s >>= 1) {
    if (threadIdx.x < s) sd[threadIdx.x] += sd[threadIdx.x + s];
    __syncthreads();
  }
  if (threadIdx.x == 0) atomicAdd(&ws->mse_num, sd[0]);
}

__device__ __forceinline__ float sigf(float z) { return 1.0f / (1.0f + __expf(-z)); }

// pair kernel: bond loss + smooth lddt sums.  4 rows/block, 64 lanes/row.
__global__ void k_pair(const float* __restrict__ x, const float* __restrict__ xgt,
                       const float* __restrict__ mask, const float* __restrict__ tbonds,
                       WS* __restrict__ ws) {
  const int ROWS = 4;
  const int bpb = NAT / ROWS;
  int b = blockIdx.x / bpb;
  int a = (blockIdx.x % bpb) * ROWS + (threadIdx.x >> 6);
  int tx = threadIdx.x & 63;
  const float* xb = x + (size_t)b * NAT * 3;
  const float* gb = xgt + (size_t)b * NAT * 3;
  const float* mb = mask + (size_t)b * NAT;
  const float* tb = tbonds + (size_t)b * NTOK * NTOK;
  float xa0 = xb[a*3], xa1 = xb[a*3+1], xa2 = xb[a*3+2];
  float ga0 = gb[a*3], ga1 = gb[a*3+1], ga2 = gb[a*3+2];
  float ma = mb[a];
  float nuca = ws->nuc[b*NAT + a];
  float liga = ws->lig[b*NAT + a];
  const float* tbrow = tb + (size_t)ws->tok[b*NAT + a] * NTOK;
  double bnum = 0, bden = 0, cemA = 0, cmA = 0;
  for (int c = tx; c < NAT; c += 64) {
    float mc = mb[c];
    float pm = ma * mc;
    float d0 = xa0 - xb[c*3], d1 = xa1 - xb[c*3+1], d2 = xa2 - xb[c*3+2];
    float dx = sqrtf(d0*d0 + d1*d1 + d2*d2);
    float e0 = ga0 - gb[c*3], e1 = ga1 - gb[c*3+1], e2 = ga2 - gb[c*3+2];
    float dg = sqrtf(e0*e0 + e1*e1 + e2*e2);
    float bm = tbrow[ws->tok[b*NAT + c]] * liga * ws->pol[b*NAT + c] * pm;
    float diff = dx - dg;
    bnum += (double)(diff * diff * bm);
    bden += (double)bm;
    if (a != c) {
      float dd = fabsf(dg - dx);
      float e = 0.25f * (sigf(0.5f - dd) + sigf(1.0f - dd) + sigf(2.0f - dd) + sigf(4.0f - dd));
      float cc = (dg < 30.0f ? nuca : 0.0f) + (dg < 15.0f ? (1.0f - nuca) : 0.0f);
      cemA += (double)(cc * e * pm);
      cmA  += (double)(cc * pm);
    }
  }
  __shared__ double sd[256];
  double vals[4] = { bnum, bden, cemA, cmA };
  double* dst[4] = { &ws->bond_num[b], &ws->bond_den[b], &ws->cem[b], &ws->cm[b] };
  for (int k = 0; k < 4; k++) {
    sd[threadIdx.x] = vals[k];
    __syncthreads();
    for (int s = 128; s > 0; s >>= 1) {
      if (threadIdx.x < s) sd[threadIdx.x] += sd[threadIdx.x + s];
      __syncthreads();
    }
    if (threadIdx.x == 0) atomicAdd(dst[k], sd[0]);
    __syncthreads();
  }
}

__global__ void k_final(WS* __restrict__ ws, float* __restrict__ out) {
  if (threadIdx.x != 0 || blockIdx.x != 0) return;
  const double wt = (4.0*4.0 + 16.0*16.0) / ((4.0+16.0)*(4.0+16.0));  // 0.68
  double lsum = 0.0;
  for (int b = 0; b < BB; b++) {
    double lmse  = ws->mse_num / (3.0 * ws->red[b][0]);
    double lbond = ws->bond_num[b] / ws->bond_den[b];
    double lddt  = ws->cem[b] / ws->cm[b];
    lsum += wt * (lmse + lbond) + (1.0 - lddt);
  }
  out[0] = (float)(lsum / BB);
}

extern "C" void kernel_launch(void* const* d_in, const int* in_sizes, int n_in,
                              void* d_out, int out_size, void* d_ws, size_t ws_size,
                              hipStream_t stream) {
  const float* x    = (const float*)d_in[0];
  const float* xgt  = (const float*)d_in[1];
  const float* mask = (const float*)d_in[2];
  const float* A    = (const float*)d_in[3];
  const float* tb   = (const float*)d_in[4];
  const float* poly = (const float*)d_in[5];
  const float* lig  = (const float*)d_in[6];
  const float* dna  = (const float*)d_in[7];
  const float* rna  = (const float*)d_in[8];
  WS* ws = (WS*)d_ws;
  float* out = (float*)d_out;

  k_init<<<1, 128, 0, stream>>>(ws);
  k_atom<<<(BB * NAT + 255) / 256, 256, 0, stream>>>(A, poly, lig, dna, rna, ws);
  k_red<<<BB, 256, 0, stream>>>(x, xgt, mask, ws);
  k_svd<<<1, 64, 0, stream>>>(ws);
  k_mse<<<(BB * NAT + 255) / 256, 256, 0, stream>>>(x, xgt, mask, ws);
  k_pair<<<BB * (NAT / 4), 256, 0, stream>>>(x, xgt, mask, tb, ws);
  k_final<<<1, 1, 0, stream>>>(ws, out);
}

// Round 2
// 65.805 us; speedup vs baseline: 2.0908x; 2.0908x over previous
//
#include <hip/hip_runtime.h>
#include <math.h>

#define BB 2
#define NAT 2048
#define NTOK 256

struct WS {
  // f64 scalar state
  double red[BB][17];   // n, swm, Swm_x[3], Swm_xgt[3], M[9]
  double mse_num;       // global numerator (per reference semantics)
  double bond_num[BB];
  double bond_den[BB];
  double cem[BB];
  double cm[BB];
  // f32 alignment results
  float Rf[BB][9];
  float muf[BB][3];     // mean of x_gt
  float mugf[BB][3];    // mean of x
  // per-atom derived
  float wA[BB*NAT];
  float nucA[BB*NAT];
  float ligA[BB*NAT];
  // packed column data: px = {x,y,z, bitcast(tok | polbit<<8)}, pg = {gx,gy,gz, mask}
  float4 px[BB*NAT];
  float4 pg[BB*NAT];
};

// one wave per atom: token id via iota-dot + wave reduce, then gather tables + pack
__global__ __launch_bounds__(256) void k_atom(
    const float* __restrict__ x, const float* __restrict__ xgt,
    const float* __restrict__ mask, const float* __restrict__ A,
    const float* __restrict__ poly, const float* __restrict__ lig,
    const float* __restrict__ dna, const float* __restrict__ rna,
    WS* __restrict__ ws) {
  int gid = blockIdx.x * 4 + (threadIdx.x >> 6);   // atom index, 0..BB*NAT-1
  int lane = threadIdx.x & 63;
  int b = gid / NAT;
  float4 v = ((const float4*)(A + (size_t)gid * NTOK))[lane];
  float s = v.x * (float)(4*lane) + v.y * (float)(4*lane+1)
          + v.z * (float)(4*lane+2) + v.w * (float)(4*lane+3);
  for (int off = 32; off; off >>= 1) s += __shfl_xor(s, off);
  if (lane == 0) {
    int t = (int)(s + 0.5f);
    float d  = dna[b*NTOK + t], r = rna[b*NTOK + t];
    float li = lig[b*NTOK + t], po = poly[b*NTOK + t];
    float m  = mask[gid];
    ws->wA[gid]   = 1.0f + 5.0f*d + 5.0f*r + 10.0f*li;
    ws->nucA[gid] = d + r;
    ws->ligA[gid] = li;
    int meta = t | ((po != 0.0f) ? 256 : 0);
    const float* xp = x   + (size_t)gid * 3;
    const float* gp = xgt + (size_t)gid * 3;
    ws->px[gid] = make_float4(xp[0], xp[1], xp[2], __int_as_float(meta));
    ws->pg[gid] = make_float4(gp[0], gp[1], gp[2], m);
  }
}

// one block per batch: 17 weighted moments (f64) + inline 3x3 SVD on thread 0.
// Also zeroes the pair-kernel accumulators (runs before k_pair in stream).
__global__ __launch_bounds__(256) void k_redsvd(WS* __restrict__ ws) {
  int b = blockIdx.x;
  int tid = threadIdx.x;
  int lane = tid & 63;
  int wv = tid >> 6;
  double acc[17];
  for (int k = 0; k < 17; k++) acc[k] = 0.0;
  for (int a = tid; a < NAT; a += 256) {
    int gid = b * NAT + a;
    float4 p = ws->px[gid];
    float4 g = ws->pg[gid];
    float m = g.w;
    if (m == 0.0f) continue;
    double wm = (double)(ws->wA[gid] * m);
    double x0 = p.x, x1 = p.y, x2 = p.z;
    double g0 = g.x, g1 = g.y, g2 = g.z;
    acc[0] += (double)m;
    acc[1] += wm;
    acc[2] += wm*x0; acc[3] += wm*x1; acc[4] += wm*x2;
    acc[5] += wm*g0; acc[6] += wm*g1; acc[7] += wm*g2;
    acc[8]  += wm*x0*g0; acc[9]  += wm*x0*g1; acc[10] += wm*x0*g2;
    acc[11] += wm*x1*g0; acc[12] += wm*x1*g1; acc[13] += wm*x1*g2;
    acc[14] += wm*x2*g0; acc[15] += wm*x2*g1; acc[16] += wm*x2*g2;
  }
  for (int k = 0; k < 17; k++)
    for (int off = 32; off; off >>= 1) acc[k] += __shfl_xor(acc[k], off);
  __shared__ double part[4][17];
  if (lane == 0)
    for (int k = 0; k < 17; k++) part[wv][k] = acc[k];
  __syncthreads();
  if (tid < 17)
    ws->red[b][tid] = part[0][tid] + part[1][tid] + part[2][tid] + part[3][tid];
  __syncthreads();
  if (tid == 0) {
    const double* red = ws->red[b];
    double swm = red[1];
    double mug[3] = { red[2]/swm, red[3]/swm, red[4]/swm };  // mean x
    double mu[3]  = { red[5]/swm, red[6]/swm, red[7]/swm };  // mean x_gt
    double H[3][3];
    for (int i = 0; i < 3; i++)
      for (int j = 0; j < 3; j++)
        H[i][j] = red[8 + 3*i + j] - swm * mug[i] * mu[j];
    double Km[3][3];
    for (int i = 0; i < 3; i++)
      for (int j = 0; j < 3; j++)
        Km[i][j] = H[0][i]*H[0][j] + H[1][i]*H[1][j] + H[2][i]*H[2][j];
    double V[3][3] = {{1,0,0},{0,1,0},{0,0,1}};
    for (int sweep = 0; sweep < 30; sweep++) {
      for (int p = 0; p < 2; p++) {
        for (int q = p + 1; q < 3; q++) {
          double apq = Km[p][q];
          if (fabs(apq) < 1e-300) continue;
          double theta = (Km[q][q] - Km[p][p]) / (2.0 * apq);
          double t = 1.0 / (fabs(theta) + sqrt(theta*theta + 1.0));
          if (theta < 0) t = -t;
          double c = 1.0 / sqrt(t*t + 1.0), sn = t * c;
          for (int k = 0; k < 3; k++) {
            double akp = Km[k][p], akq = Km[k][q];
            Km[k][p] = c*akp - sn*akq;
            Km[k][q] = sn*akp + c*akq;
          }
          for (int k = 0; k < 3; k++) {
            double apk = Km[p][k], aqk = Km[q][k];
            Km[p][k] = c*apk - sn*aqk;
            Km[q][k] = sn*apk + c*aqk;
          }
          for (int k = 0; k < 3; k++) {
            double vkp = V[k][p], vkq = V[k][q];
            V[k][p] = c*vkp - sn*vkq;
            V[k][q] = sn*vkp + c*vkq;
          }
        }
      }
    }
    double ev[3] = { Km[0][0], Km[1][1], Km[2][2] };
    int id[3] = {0, 1, 2};
    for (int i = 0; i < 2; i++)
      for (int j = i + 1; j < 3; j++)
        if (ev[id[j]] > ev[id[i]]) { int tmp = id[i]; id[i] = id[j]; id[j] = tmp; }
    double Uc[3][3], Vc[3][3], S[3];
    for (int k = 0; k < 3; k++) {
      int e = id[k];
      double v0 = V[0][e], v1 = V[1][e], v2 = V[2][e];
      Vc[k][0] = v0; Vc[k][1] = v1; Vc[k][2] = v2;
      double u0 = H[0][0]*v0 + H[0][1]*v1 + H[0][2]*v2;
      double u1 = H[1][0]*v0 + H[1][1]*v1 + H[1][2]*v2;
      double u2 = H[2][0]*v0 + H[2][1]*v1 + H[2][2]*v2;
      double nrm = sqrt(u0*u0 + u1*u1 + u2*u2);
      S[k] = nrm;
      if (nrm > 1e-12) { u0 /= nrm; u1 /= nrm; u2 /= nrm; }
      Uc[k][0] = u0; Uc[k][1] = u1; Uc[k][2] = u2;
    }
    if (S[2] <= 1e-12 * (S[0] > 0 ? S[0] : 1.0)) {
      Uc[2][0] = Uc[0][1]*Uc[1][2] - Uc[0][2]*Uc[1][1];
      Uc[2][1] = Uc[0][2]*Uc[1][0] - Uc[0][0]*Uc[1][2];
      Uc[2][2] = Uc[0][0]*Uc[1][1] - Uc[0][1]*Uc[1][0];
    }
    double detU = Uc[0][0]*(Uc[1][1]*Uc[2][2]-Uc[1][2]*Uc[2][1])
                - Uc[1][0]*(Uc[0][1]*Uc[2][2]-Uc[0][2]*Uc[2][1])
                + Uc[2][0]*(Uc[0][1]*Uc[1][2]-Uc[0][2]*Uc[1][1]);
    double detV = Vc[0][0]*(Vc[1][1]*Vc[2][2]-Vc[1][2]*Vc[2][1])
                - Vc[1][0]*(Vc[0][1]*Vc[2][2]-Vc[0][2]*Vc[2][1])
                + Vc[2][0]*(Vc[0][1]*Vc[1][2]-Vc[0][2]*Vc[1][1]);
    double dsign = (detU * detV < 0.0) ? -1.0 : 1.0;
    for (int i = 0; i < 3; i++)
      for (int j = 0; j < 3; j++)
        ws->Rf[b][3*i+j] = (float)(Uc[0][i]*Vc[0][j] + Uc[1][i]*Vc[1][j]
                                   + dsign*Uc[2][i]*Vc[2][j]);
    for (int i = 0; i < 3; i++) {
      ws->muf[b][i]  = (float)mu[i];
      ws->mugf[b][i] = (float)mug[i];
    }
    // zero pair-kernel accumulators (k_pair runs strictly after this kernel)
    ws->bond_num[b] = 0.0; ws->bond_den[b] = 0.0;
    ws->cem[b] = 0.0; ws->cm[b] = 0.0;
    if (b == 0) ws->mse_num = 0.0;
  }
}

__device__ __forceinline__ float sigf(float z) {
  return __builtin_amdgcn_rcpf(1.0f + __expf(-z));
}

// pair kernel: bond + lddt sums, f32 inner accumulation; mse term fused (lane 0 per row)
__global__ __launch_bounds__(256) void k_pair(const float* __restrict__ tb,
                                              WS* __restrict__ ws) {
  const int bpb = NAT / 4;
  int b = blockIdx.x / bpb;
  int a = (blockIdx.x % bpb) * 4 + (threadIdx.x >> 6);
  int tx = threadIdx.x & 63;
  int rowi = b * NAT + a;
  const float4* __restrict__ px = ws->px + (size_t)b * NAT;
  const float4* __restrict__ pg = ws->pg + (size_t)b * NAT;
  float4 pa = px[a];
  float4 ga = pg[a];
  float ma = ga.w;
  float nuca = ws->nucA[rowi];
  float liga = ws->ligA[rowi];
  int ta = __float_as_int(pa.w) & 255;
  const float* __restrict__ tbrow = tb + ((size_t)b * NTOK + ta) * NTOK;

  float bnum = 0.f, bden = 0.f, cemv = 0.f, cmv = 0.f;
  #pragma unroll 4
  for (int c = tx; c < NAT; c += 64) {
    float4 pc = px[c];
    float4 gc = pg[c];
    int meta = __float_as_int(pc.w);
    float pm = ma * gc.w;
    float d0 = pa.x-pc.x, d1 = pa.y-pc.y, d2 = pa.z-pc.z;
    float dxv = sqrtf(d0*d0 + d1*d1 + d2*d2);
    float e0 = ga.x-gc.x, e1 = ga.y-gc.y, e2 = ga.z-gc.z;
    float dgv = sqrtf(e0*e0 + e1*e1 + e2*e2);
    float tbv = tbrow[meta & 255];
    float bm = ((meta & 256) ? tbv : 0.0f) * liga * pm;
    float diff = dxv - dgv;
    bnum += diff * diff * bm;
    bden += bm;
    float dd = fabsf(diff);
    float e = sigf(0.5f-dd) + sigf(1.0f-dd) + sigf(2.0f-dd) + sigf(4.0f-dd);
    float cc = (dgv < 30.0f ? nuca : 0.0f) + (dgv < 15.0f ? 1.0f - nuca : 0.0f);
    float pml = (c == a) ? 0.0f : pm;
    cemv += cc * e * pml;
    cmv  += cc * pml;
  }
  cemv *= 0.25f;

  float msef = 0.0f;
  if (tx == 0 && ma != 0.0f) {
    const float* R = ws->Rf[b];
    const float* mu = ws->muf[b];
    const float* mug = ws->mugf[b];
    float c0 = ga.x - mu[0], c1 = ga.y - mu[1], c2 = ga.z - mu[2];
    float a0 = R[0]*c0 + R[1]*c1 + R[2]*c2 + mug[0];
    float a1 = R[3]*c0 + R[4]*c1 + R[5]*c2 + mug[1];
    float a2 = R[6]*c0 + R[7]*c1 + R[8]*c2 + mug[2];
    float q0 = pa.x - a0, q1 = pa.y - a1, q2 = pa.z - a2;
    msef = ws->wA[rowi] * ma * (q0*q0 + q1*q1 + q2*q2);
  }

  float vals[5] = { bnum, bden, cemv, cmv, msef };
  for (int k = 0; k < 5; k++)
    for (int off = 32; off; off >>= 1) vals[k] += __shfl_xor(vals[k], off);
  __shared__ double part[4][5];
  int wv = threadIdx.x >> 6;
  if (tx == 0)
    for (int k = 0; k < 5; k++) part[wv][k] = (double)vals[k];
  __syncthreads();
  if (threadIdx.x < 5) {
    int k = threadIdx.x;
    double s = part[0][k] + part[1][k] + part[2][k] + part[3][k];
    double* dst = (k == 0) ? &ws->bond_num[b] : (k == 1) ? &ws->bond_den[b]
                : (k == 2) ? &ws->cem[b]      : (k == 3) ? &ws->cm[b]
                : &ws->mse_num;
    atomicAdd(dst, s);
  }
}

__global__ void k_final(WS* __restrict__ ws, float* __restrict__ out) {
  if (threadIdx.x != 0 || blockIdx.x != 0) return;
  const double wt = (4.0*4.0 + 16.0*16.0) / ((4.0+16.0)*(4.0+16.0));  // 0.68
  double lsum = 0.0;
  for (int b = 0; b < BB; b++) {
    double lmse  = ws->mse_num / (3.0 * ws->red[b][0]);
    double lbond = ws->bond_num[b] / ws->bond_den[b];
    double lddt  = ws->cem[b] / ws->cm[b];
    lsum += wt * (lmse + lbond) + (1.0 - lddt);
  }
  out[0] = (float)(lsum / BB);
}

extern "C" void kernel_launch(void* const* d_in, const int* in_sizes, int n_in,
                              void* d_out, int out_size, void* d_ws, size_t ws_size,
                              hipStream_t stream) {
  const float* x    = (const float*)d_in[0];
  const float* xgt  = (const float*)d_in[1];
  const float* mask = (const float*)d_in[2];
  const float* A    = (const float*)d_in[3];
  const float* tb   = (const float*)d_in[4];
  const float* poly = (const float*)d_in[5];
  const float* lig  = (const float*)d_in[6];
  const float* dna  = (const float*)d_in[7];
  const float* rna  = (const float*)d_in[8];
  WS* ws = (WS*)d_ws;
  float* out = (float*)d_out;

  k_atom<<<BB * NAT / 4, 256, 0, stream>>>(x, xgt, mask, A, poly, lig, dna, rna, ws);
  k_redsvd<<<BB, 256, 0, stream>>>(ws);
  k_pair<<<BB * (NAT / 4), 256, 0, stream>>>(tb, ws);
  k_final<<<1, 1, 0, stream>>>(ws, out);
}

// Round 3
// 59.111 us; speedup vs baseline: 2.3275x; 1.1132x over previous
//
#include <hip/hip_runtime.h>
#include <math.h>

#define BB 2
#define NAT 2048
#define NTOK 256

struct WS {
  // f64 scalar state
  double red[BB][17];   // n, swm, Swm_x[3], Swm_xgt[3], M[9]
  double mse_num;       // global numerator (per reference semantics)
  double bond_num[BB];
  double bond_den[BB];
  double cem[BB];
  double cm[BB];
  // f32 alignment results
  float Rf[BB][9];
  float muf[BB][3];     // mean of x_gt
  float mugf[BB][3];    // mean of x
  // per-atom derived
  float wA[BB*NAT];
  float nucA[BB*NAT];
  float ligA[BB*NAT];
  // packed column data: px = {x,y,z, bitcast(tok | polbit<<8)}, pg = {gx,gy,gz, mask}
  float4 px[BB*NAT];
  float4 pg[BB*NAT];
};

// one wave per atom: token id via iota-dot + wave reduce, then gather tables + pack
__global__ __launch_bounds__(256) void k_atom(
    const float* __restrict__ x, const float* __restrict__ xgt,
    const float* __restrict__ mask, const float* __restrict__ A,
    const float* __restrict__ poly, const float* __restrict__ lig,
    const float* __restrict__ dna, const float* __restrict__ rna,
    WS* __restrict__ ws) {
  int gid = blockIdx.x * 4 + (threadIdx.x >> 6);   // atom index, 0..BB*NAT-1
  int lane = threadIdx.x & 63;
  int b = gid / NAT;
  float4 v = ((const float4*)(A + (size_t)gid * NTOK))[lane];
  float s = v.x * (float)(4*lane) + v.y * (float)(4*lane+1)
          + v.z * (float)(4*lane+2) + v.w * (float)(4*lane+3);
  for (int off = 32; off; off >>= 1) s += __shfl_xor(s, off);
  if (lane == 0) {
    int t = (int)(s + 0.5f);
    float d  = dna[b*NTOK + t], r = rna[b*NTOK + t];
    float li = lig[b*NTOK + t], po = poly[b*NTOK + t];
    float m  = mask[gid];
    ws->wA[gid]   = 1.0f + 5.0f*d + 5.0f*r + 10.0f*li;
    ws->nucA[gid] = d + r;
    ws->ligA[gid] = li;
    int meta = t | ((po != 0.0f) ? 256 : 0);
    const float* xp = x   + (size_t)gid * 3;
    const float* gp = xgt + (size_t)gid * 3;
    ws->px[gid] = make_float4(xp[0], xp[1], xp[2], __int_as_float(meta));
    ws->pg[gid] = make_float4(gp[0], gp[1], gp[2], m);
  }
}

// one block per batch: 17 weighted moments (f64) + inline 3x3 SVD on thread 0.
// Also zeroes the pair-kernel accumulators (runs before k_pair in stream).
__global__ __launch_bounds__(256) void k_redsvd(WS* __restrict__ ws) {
  int b = blockIdx.x;
  int tid = threadIdx.x;
  int lane = tid & 63;
  int wv = tid >> 6;
  double acc[17];
  for (int k = 0; k < 17; k++) acc[k] = 0.0;
  for (int a = tid; a < NAT; a += 256) {
    int gid = b * NAT + a;
    float4 p = ws->px[gid];
    float4 g = ws->pg[gid];
    float m = g.w;
    if (m == 0.0f) continue;
    double wm = (double)(ws->wA[gid] * m);
    double x0 = p.x, x1 = p.y, x2 = p.z;
    double g0 = g.x, g1 = g.y, g2 = g.z;
    acc[0] += (double)m;
    acc[1] += wm;
    acc[2] += wm*x0; acc[3] += wm*x1; acc[4] += wm*x2;
    acc[5] += wm*g0; acc[6] += wm*g1; acc[7] += wm*g2;
    acc[8]  += wm*x0*g0; acc[9]  += wm*x0*g1; acc[10] += wm*x0*g2;
    acc[11] += wm*x1*g0; acc[12] += wm*x1*g1; acc[13] += wm*x1*g2;
    acc[14] += wm*x2*g0; acc[15] += wm*x2*g1; acc[16] += wm*x2*g2;
  }
  for (int k = 0; k < 17; k++)
    for (int off = 32; off; off >>= 1) acc[k] += __shfl_xor(acc[k], off);
  __shared__ double part[4][17];
  if (lane == 0)
    for (int k = 0; k < 17; k++) part[wv][k] = acc[k];
  __syncthreads();
  if (tid < 17)
    ws->red[b][tid] = part[0][tid] + part[1][tid] + part[2][tid] + part[3][tid];
  __syncthreads();
  if (tid == 0) {
    const double* red = ws->red[b];
    double swm = red[1];
    double mug[3] = { red[2]/swm, red[3]/swm, red[4]/swm };  // mean x
    double mu[3]  = { red[5]/swm, red[6]/swm, red[7]/swm };  // mean x_gt
    double H[3][3];
    for (int i = 0; i < 3; i++)
      for (int j = 0; j < 3; j++)
        H[i][j] = red[8 + 3*i + j] - swm * mug[i] * mu[j];
    double Km[3][3];
    for (int i = 0; i < 3; i++)
      for (int j = 0; j < 3; j++)
        Km[i][j] = H[0][i]*H[0][j] + H[1][i]*H[1][j] + H[2][i]*H[2][j];
    double V[3][3] = {{1,0,0},{0,1,0},{0,0,1}};
    // Jacobi with early exit: 3x3 converges quadratically, ~4-6 sweeps to f64 eps
    for (int sweep = 0; sweep < 15; sweep++) {
      double off2 = Km[0][1]*Km[0][1] + Km[0][2]*Km[0][2] + Km[1][2]*Km[1][2];
      double dia2 = Km[0][0]*Km[0][0] + Km[1][1]*Km[1][1] + Km[2][2]*Km[2][2];
      if (off2 < 1e-26 * dia2 + 1e-300) break;
      for (int p = 0; p < 2; p++) {
        for (int q = p + 1; q < 3; q++) {
          double apq = Km[p][q];
          if (fabs(apq) < 1e-300) continue;
          double theta = (Km[q][q] - Km[p][p]) / (2.0 * apq);
          double t = 1.0 / (fabs(theta) + sqrt(theta*theta + 1.0));
          if (theta < 0) t = -t;
          double c = 1.0 / sqrt(t*t + 1.0), sn = t * c;
          for (int k = 0; k < 3; k++) {
            double akp = Km[k][p], akq = Km[k][q];
            Km[k][p] = c*akp - sn*akq;
            Km[k][q] = sn*akp + c*akq;
          }
          for (int k = 0; k < 3; k++) {
            double apk = Km[p][k], aqk = Km[q][k];
            Km[p][k] = c*apk - sn*aqk;
            Km[q][k] = sn*apk + c*aqk;
          }
          for (int k = 0; k < 3; k++) {
            double vkp = V[k][p], vkq = V[k][q];
            V[k][p] = c*vkp - sn*vkq;
            V[k][q] = sn*vkp + c*vkq;
          }
        }
      }
    }
    double ev[3] = { Km[0][0], Km[1][1], Km[2][2] };
    int id[3] = {0, 1, 2};
    for (int i = 0; i < 2; i++)
      for (int j = i + 1; j < 3; j++)
        if (ev[id[j]] > ev[id[i]]) { int tmp = id[i]; id[i] = id[j]; id[j] = tmp; }
    double Uc[3][3], Vc[3][3], S[3];
    for (int k = 0; k < 3; k++) {
      int e = id[k];
      double v0 = V[0][e], v1 = V[1][e], v2 = V[2][e];
      Vc[k][0] = v0; Vc[k][1] = v1; Vc[k][2] = v2;
      double u0 = H[0][0]*v0 + H[0][1]*v1 + H[0][2]*v2;
      double u1 = H[1][0]*v0 + H[1][1]*v1 + H[1][2]*v2;
      double u2 = H[2][0]*v0 + H[2][1]*v1 + H[2][2]*v2;
      double nrm = sqrt(u0*u0 + u1*u1 + u2*u2);
      S[k] = nrm;
      if (nrm > 1e-12) { u0 /= nrm; u1 /= nrm; u2 /= nrm; }
      Uc[k][0] = u0; Uc[k][1] = u1; Uc[k][2] = u2;
    }
    if (S[2] <= 1e-12 * (S[0] > 0 ? S[0] : 1.0)) {
      Uc[2][0] = Uc[0][1]*Uc[1][2] - Uc[0][2]*Uc[1][1];
      Uc[2][1] = Uc[0][2]*Uc[1][0] - Uc[0][0]*Uc[1][2];
      Uc[2][2] = Uc[0][0]*Uc[1][1] - Uc[0][1]*Uc[1][0];
    }
    double detU = Uc[0][0]*(Uc[1][1]*Uc[2][2]-Uc[1][2]*Uc[2][1])
                - Uc[1][0]*(Uc[0][1]*Uc[2][2]-Uc[0][2]*Uc[2][1])
                + Uc[2][0]*(Uc[0][1]*Uc[1][2]-Uc[0][2]*Uc[1][1]);
    double detV = Vc[0][0]*(Vc[1][1]*Vc[2][2]-Vc[1][2]*Vc[2][1])
                - Vc[1][0]*(Vc[0][1]*Vc[2][2]-Vc[0][2]*Vc[2][1])
                + Vc[2][0]*(Vc[0][1]*Vc[1][2]-Vc[0][2]*Vc[1][1]);
    double dsign = (detU * detV < 0.0) ? -1.0 : 1.0;
    for (int i = 0; i < 3; i++)
      for (int j = 0; j < 3; j++)
        ws->Rf[b][3*i+j] = (float)(Uc[0][i]*Vc[0][j] + Uc[1][i]*Vc[1][j]
                                   + dsign*Uc[2][i]*Vc[2][j]);
    for (int i = 0; i < 3; i++) {
      ws->muf[b][i]  = (float)mu[i];
      ws->mugf[b][i] = (float)mug[i];
    }
    // zero pair-kernel accumulators (k_pair runs strictly after this kernel)
    ws->bond_num[b] = 0.0; ws->bond_den[b] = 0.0;
    ws->cem[b] = 0.0; ws->cm[b] = 0.0;
    if (b == 0) ws->mse_num = 0.0;
  }
}

// pair kernel: bond + lddt sums, f32 inner accumulation; mse term fused (lane 0 per row)
__global__ __launch_bounds__(256) void k_pair(const float* __restrict__ tb,
                                              WS* __restrict__ ws) {
  const int bpb = NAT / 4;
  int b = blockIdx.x / bpb;
  int a = (blockIdx.x % bpb) * 4 + (threadIdx.x >> 6);
  int tx = threadIdx.x & 63;
  int rowi = b * NAT + a;
  const float4* __restrict__ px = ws->px + (size_t)b * NAT;
  const float4* __restrict__ pg = ws->pg + (size_t)b * NAT;
  float4 pa = px[a];
  float4 ga = pg[a];
  float ma = ga.w;
  float nuca = ws->nucA[rowi];
  float lm = ws->ligA[rowi] * ma;       // row-constant bond gate
  bool dob = (lm != 0.0f);              // ~18% of rows
  float thresh = (nuca > 0.5f) ? 30.0f : 15.0f;  // nuc is binary by construction
  int ta = __float_as_int(pa.w) & 255;
  const float* __restrict__ tbrow = tb + ((size_t)b * NTOK + ta) * NTOK;

  // sig(a-dd) = 1/(1 + e^dd * e^-a); one exp, four rcp.  exp overflow -> rcp(inf)=0, correct.
  const float K1 = 0.60653066f;   // e^-0.5
  const float K2 = 0.36787944f;   // e^-1
  const float K3 = 0.13533528f;   // e^-2
  const float K4 = 0.018315639f;  // e^-4

  float bnum = 0.f, bden = 0.f, cemv = 0.f, cmv = 0.f;
  #pragma unroll 4
  for (int c = tx; c < NAT; c += 64) {
    float4 pc = px[c];
    float4 gc = pg[c];
    float pm = ma * gc.w;
    float d0 = pa.x-pc.x, d1 = pa.y-pc.y, d2 = pa.z-pc.z;
    float dxv = sqrtf(d0*d0 + d1*d1 + d2*d2);
    float e0 = ga.x-gc.x, e1 = ga.y-gc.y, e2 = ga.z-gc.z;
    float dgv = sqrtf(e0*e0 + e1*e1 + e2*e2);
    float diff = dxv - dgv;
    if (dob) {
      int meta = __float_as_int(pc.w);
      float tbv = tbrow[meta & 255];
      float bm = ((meta & 256) ? tbv : 0.0f) * lm * gc.w;
      bnum += diff * diff * bm;
      bden += bm;
    }
    float dd = fabsf(diff);
    float E = __expf(dd);
    float e = __builtin_amdgcn_rcpf(1.0f + E*K1) + __builtin_amdgcn_rcpf(1.0f + E*K2)
            + __builtin_amdgcn_rcpf(1.0f + E*K3) + __builtin_amdgcn_rcpf(1.0f + E*K4);
    float pml = ((c == a) || (dgv >= thresh)) ? 0.0f : pm;
    cemv += e * pml;
    cmv  += pml;
  }
  cemv *= 0.25f;

  float msef = 0.0f;
  if (tx == 0 && ma != 0.0f) {
    const float* R = ws->Rf[b];
    const float* mu = ws->muf[b];
    const float* mug = ws->mugf[b];
    float c0 = ga.x - mu[0], c1 = ga.y - mu[1], c2 = ga.z - mu[2];
    float a0 = R[0]*c0 + R[1]*c1 + R[2]*c2 + mug[0];
    float a1 = R[3]*c0 + R[4]*c1 + R[5]*c2 + mug[1];
    float a2 = R[6]*c0 + R[7]*c1 + R[8]*c2 + mug[2];
    float q0 = pa.x - a0, q1 = pa.y - a1, q2 = pa.z - a2;
    msef = ws->wA[rowi] * ma * (q0*q0 + q1*q1 + q2*q2);
  }

  float vals[5] = { bnum, bden, cemv, cmv, msef };
  for (int k = 0; k < 5; k++)
    for (int off = 32; off; off >>= 1) vals[k] += __shfl_xor(vals[k], off);
  __shared__ double part[4][5];
  int wv = threadIdx.x >> 6;
  if (tx == 0)
    for (int k = 0; k < 5; k++) part[wv][k] = (double)vals[k];
  __syncthreads();
  if (threadIdx.x < 5) {
    int k = threadIdx.x;
    double s = part[0][k] + part[1][k] + part[2][k] + part[3][k];
    double* dst = (k == 0) ? &ws->bond_num[b] : (k == 1) ? &ws->bond_den[b]
                : (k == 2) ? &ws->cem[b]      : (k == 3) ? &ws->cm[b]
                : &ws->mse_num;
    atomicAdd(dst, s);
  }
}

__global__ void k_final(WS* __restrict__ ws, float* __restrict__ out) {
  if (threadIdx.x != 0 || blockIdx.x != 0) return;
  const double wt = (4.0*4.0 + 16.0*16.0) / ((4.0+16.0)*(4.0+16.0));  // 0.68
  double lsum = 0.0;
  for (int b = 0; b < BB; b++) {
    double lmse  = ws->mse_num / (3.0 * ws->red[b][0]);
    double lbond = ws->bond_num[b] / ws->bond_den[b];
    double lddt  = ws->cem[b] / ws->cm[b];
    lsum += wt * (lmse + lbond) + (1.0 - lddt);
  }
  out[0] = (float)(lsum / BB);
}

extern "C" void kernel_launch(void* const* d_in, const int* in_sizes, int n_in,
                              void* d_out, int out_size, void* d_ws, size_t ws_size,
                              hipStream_t stream) {
  const float* x    = (const float*)d_in[0];
  const float* xgt  = (const float*)d_in[1];
  const float* mask = (const float*)d_in[2];
  const float* A    = (const float*)d_in[3];
  const float* tb   = (const float*)d_in[4];
  const float* poly = (const float*)d_in[5];
  const float* lig  = (const float*)d_in[6];
  const float* dna  = (const float*)d_in[7];
  const float* rna  = (const float*)d_in[8];
  WS* ws = (WS*)d_ws;
  float* out = (float*)d_out;

  k_atom<<<BB * NAT / 4, 256, 0, stream>>>(x, xgt, mask, A, poly, lig, dna, rna, ws);
  k_redsvd<<<BB, 256, 0, stream>>>(ws);
  k_pair<<<BB * (NAT / 4), 256, 0, stream>>>(tb, ws);
  k_final<<<1, 1, 0, stream>>>(ws, out);
}